// Round 1
// baseline (1487.431 us; speedup 1.0000x reference)
//
#include <hip/hip_runtime.h>
#include <hip/hip_bf16.h>

#define NN 50000
#define KI 8
#define H 128
#define XD 32
#define SD 27
// combined = [x(32) | h_self(128) | nc(128) | static_proj(128)] = 416
#define CIN 416
#define ZOUT 512

__device__ __forceinline__ float sigmoidf_(float x) {
    return 1.0f / (1.0f + __expf(-x));
}
__device__ __forceinline__ float dot4_(float4 a, float4 b) {
    return a.x * b.x + a.y * b.y + a.z * b.z + a.w * b.w;
}

// ---------------------------------------------------------------------------
// Kernel 1: neighbor context. 8 nodes per block, 256 threads.
// thread t: output channel o = t&127, node-half g = t>>7 (4 nodes each).
// ---------------------------------------------------------------------------
__global__ __launch_bounds__(256) void k_neighbor(
    const float* __restrict__ hself_g, const float* __restrict__ hin_g,
    const unsigned char* __restrict__ valid_raw,
    const float* __restrict__ Wn, const float* __restrict__ Wg,
    const float* __restrict__ bg, float* __restrict__ nc)
{
    __shared__ float4 hin_s[8 * KI * (H / 4)];  // [8 nodes][8 k][32 float4] = 32KB
    __shared__ float4 hs_s[8 * (H / 4)];        // [8][32] = 4KB
    __shared__ int flag8;

    const int t = threadIdx.x;
    const int nb = blockIdx.x * 8;

    // --- detect inflow_valid element width (bool8 vs 4-byte int/float) ---
    {
        int loc = 0;
        if (t < 64) {
            #pragma unroll
            for (int i = 0; i < 16; ++i) loc |= valid_raw[4 * (t * 16 + i) + 1];
        }
        int any = __any(loc != 0);
        if (t == 0) flag8 = any;
    }

    // --- stage h_inflows (8*8*128 f32) and h_self (8*128 f32) ---
    const float4* src_hin = (const float4*)(hin_g + (size_t)nb * KI * H);
    #pragma unroll
    for (int i = 0; i < 8; ++i) hin_s[t + i * 256] = src_hin[t + i * 256];
    const float4* src_hs = (const float4*)(hself_g + (size_t)nb * H);
    hs_s[t] = src_hs[t];
    __syncthreads();

    const int o = t & 127;
    const int g = t >> 7;

    float msg[4][KI], gat[4][KI], gh[4];
    #pragma unroll
    for (int j = 0; j < 4; ++j) {
        gh[j] = 0.f;
        #pragma unroll
        for (int k = 0; k < KI; ++k) { msg[j][k] = 0.f; gat[j][k] = 0.f; }
    }

    const float4* Wn4  = (const float4*)(Wn + (size_t)o * H);
    const float4* Wg4a = (const float4*)(Wg + (size_t)o * 2 * H);
    const float4* Wg4b = (const float4*)(Wg + (size_t)o * 2 * H + H);

    for (int d4 = 0; d4 < H / 4; ++d4) {
        float4 wn = Wn4[d4];
        float4 w0 = Wg4a[d4];
        float4 w1 = Wg4b[d4];
        #pragma unroll
        for (int j = 0; j < 4; ++j) {
            const int node = g * 4 + j;
            float4 hs = hs_s[node * 32 + d4];
            gh[j] += dot4_(w1, hs);
            #pragma unroll
            for (int k = 0; k < KI; ++k) {
                float4 hv = hin_s[(node * KI + k) * 32 + d4];
                msg[j][k] += dot4_(wn, hv);
                gat[j][k] += dot4_(w0, hv);
            }
        }
    }

    const float bgo = bg[o];
    const unsigned int* valid32 = (const unsigned int*)valid_raw;
    const int f8 = flag8;
    #pragma unroll
    for (int j = 0; j < 4; ++j) {
        const int n = nb + g * 4 + j;
        float acc = 0.f;
        #pragma unroll
        for (int k = 0; k < KI; ++k) {
            bool v = f8 ? (valid_raw[n * KI + k] != 0) : (valid32[n * KI + k] != 0u);
            if (v) acc += sigmoidf_(gat[j][k] + gh[j] + bgo) * msg[j][k];
        }
        nc[(size_t)n * H + o] = acc;
    }
}

// ---------------------------------------------------------------------------
// Kernel 2: static proj + LSTM matvec + elementwise + LayerNorm.
// 16 nodes per block, 256 threads. Thread t computes z rows t and t+256.
// ---------------------------------------------------------------------------
__global__ __launch_bounds__(256) void k_lstm(
    const float* __restrict__ x_g, const float* __restrict__ hself_g,
    const float* __restrict__ cself_g, const float* __restrict__ stat_g,
    const float* __restrict__ nc,
    const float* __restrict__ Ws, const float* __restrict__ bs,
    const float* __restrict__ Wl, const float* __restrict__ bl,
    const float* __restrict__ lnw, const float* __restrict__ lnb,
    float* __restrict__ h_out, float* __restrict__ c_out)
{
    __shared__ float4 comb4[16 * (CIN / 4)];  // 16 x 416 f32 = 26.6KB
    __shared__ float  zsh[16 * ZOUT];         // 32KB
    __shared__ float  stat_s[16 * SD];        // 1.7KB
    float* comb = (float*)comb4;

    const int t = threadIdx.x;
    const int nb = blockIdx.x * 16;

    // --- stage combined segments ---
    #pragma unroll
    for (int i = 0; i < 2; ++i) {  // x: 16*32 = 512
        int idx = t + i * 256;
        comb[(idx >> 5) * CIN + (idx & 31)] = x_g[(size_t)nb * XD + idx];
    }
    #pragma unroll
    for (int i = 0; i < 8; ++i) {  // h_self: 16*128 = 2048
        int idx = t + i * 256;
        comb[(idx >> 7) * CIN + 32 + (idx & 127)] = hself_g[(size_t)nb * H + idx];
    }
    #pragma unroll
    for (int i = 0; i < 8; ++i) {  // nc
        int idx = t + i * 256;
        comb[(idx >> 7) * CIN + 160 + (idx & 127)] = nc[(size_t)nb * H + idx];
    }
    stat_s[t] = stat_g[(size_t)nb * SD + t];
    if (t < 16 * SD - 256) stat_s[t + 256] = stat_g[(size_t)nb * SD + t + 256];
    __syncthreads();

    // --- static projection into comb[.., 288:416] ---
    {
        const int o = t & 127, jg = t >> 7;
        #pragma unroll
        for (int jj = 0; jj < 8; ++jj) {
            const int j = jg * 8 + jj;
            float s = bs[o];
            #pragma unroll
            for (int c = 0; c < SD; ++c) s += Ws[o * SD + c] * stat_s[j * SD + c];
            comb[j * CIN + 288 + o] = s;
        }
    }
    __syncthreads();

    // --- z = combined @ Wl^T : thread t -> rows t and t+256 of z ---
    float acc0[16], acc1[16];
    #pragma unroll
    for (int j = 0; j < 16; ++j) { acc0[j] = 0.f; acc1[j] = 0.f; }
    const float4* W0 = (const float4*)(Wl + (size_t)t * CIN);
    const float4* W1 = (const float4*)(Wl + (size_t)(t + 256) * CIN);
    for (int d4 = 0; d4 < CIN / 4; ++d4) {
        float4 w0 = W0[d4];
        float4 w1 = W1[d4];
        #pragma unroll
        for (int j = 0; j < 16; ++j) {
            float4 cv = comb4[j * (CIN / 4) + d4];
            acc0[j] += dot4_(w0, cv);
            acc1[j] += dot4_(w1, cv);
        }
    }
    const float bl0 = bl[t], bl1 = bl[t + 256];
    #pragma unroll
    for (int j = 0; j < 16; ++j) {
        zsh[j * ZOUT + t]       = acc0[j] + bl0;
        zsh[j * ZOUT + 256 + t] = acc1[j] + bl1;
    }
    __syncthreads();

    // --- LSTM elementwise: c_new, h_pre (h_pre overwrites zsh[j][h]) ---
    {
        const int h = t & 127, jg = t >> 7;
        #pragma unroll
        for (int jj = 0; jj < 8; ++jj) {
            const int j = jg * 8 + jj;
            const size_t n = (size_t)(nb + j);
            float zi = zsh[j * ZOUT + h];
            float zf = zsh[j * ZOUT + 128 + h];
            float zo = zsh[j * ZOUT + 256 + h];
            float zg = zsh[j * ZOUT + 384 + h];
            float cn = sigmoidf_(zf) * cself_g[n * H + h] + sigmoidf_(zi) * tanhf(zg);
            c_out[n * H + h] = cn;
            zsh[j * ZOUT + h] = sigmoidf_(zo) * tanhf(cn);
        }
    }
    __syncthreads();

    // --- LayerNorm over H=128, one wave per node (4 nodes per wave) ---
    {
        const int w = t >> 6, lane = t & 63;
        #pragma unroll
        for (int jj = 0; jj < 4; ++jj) {
            const int j = w * 4 + jj;
            const size_t n = (size_t)(nb + j);
            float a = zsh[j * ZOUT + lane];
            float b = zsh[j * ZOUT + 64 + lane];
            float s = a + b, q = a * a + b * b;
            #pragma unroll
            for (int off = 1; off < 64; off <<= 1) {
                s += __shfl_xor(s, off);
                q += __shfl_xor(q, off);
            }
            float mu = s * (1.0f / 128.0f);
            float var = q * (1.0f / 128.0f) - mu * mu;
            float rstd = rsqrtf(var + 1e-5f);
            h_out[n * H + lane]      = (a - mu) * rstd * lnw[lane] + lnb[lane];
            h_out[n * H + 64 + lane] = (b - mu) * rstd * lnw[64 + lane] + lnb[64 + lane];
        }
    }
}

extern "C" void kernel_launch(void* const* d_in, const int* in_sizes, int n_in,
                              void* d_out, int out_size, void* d_ws, size_t ws_size,
                              hipStream_t stream) {
    const float* x       = (const float*)d_in[0];
    const float* h_self  = (const float*)d_in[1];
    const float* c_self  = (const float*)d_in[2];
    const float* h_inf   = (const float*)d_in[3];
    const unsigned char* valid = (const unsigned char*)d_in[4];
    const float* statp   = (const float*)d_in[5];
    const float* Wn      = (const float*)d_in[6];
    const float* Wg      = (const float*)d_in[7];
    const float* bg      = (const float*)d_in[8];
    const float* Ws      = (const float*)d_in[9];
    const float* bs      = (const float*)d_in[10];
    const float* Wl      = (const float*)d_in[11];
    const float* bl      = (const float*)d_in[12];
    const float* lnw     = (const float*)d_in[13];
    const float* lnb     = (const float*)d_in[14];

    float* h_out = (float*)d_out;
    float* c_out = h_out + (size_t)NN * H;

    // neighbor-context scratch: d_ws if big enough, else h_out region
    // (kernel 2 reads nc rows only for its own nodes before writing them).
    float* nc_buf = (ws_size >= (size_t)NN * H * sizeof(float))
                        ? (float*)d_ws : h_out;

    k_neighbor<<<NN / 8, 256, 0, stream>>>(h_self, h_inf, valid, Wn, Wg, bg, nc_buf);
    k_lstm<<<NN / 16, 256, 0, stream>>>(x, h_self, c_self, statp, nc_buf,
                                        Ws, bs, Wl, bl, lnw, lnb, h_out, c_out);
}

// Round 2
// 265.002 us; speedup vs baseline: 5.6129x; 5.6129x over previous
//
#include <hip/hip_runtime.h>
#include <hip/hip_bf16.h>

#define NN 50000
#define KI 8
#define H 128
#define XD 32
#define SD 27
#define CIN 416      // original combined width
#define CIN2 320     // fused combined: x(32)|h(128)|nc(128)|static(27)|pad(5)
#define CPAD 328     // LDS row stride (shorts) -> 656B, 2-way-free banks
#define ZOUT 512

typedef __attribute__((ext_vector_type(8))) short bf16x8;
typedef __attribute__((ext_vector_type(4))) float f32x4;
typedef __attribute__((ext_vector_type(4))) unsigned short us4;

#define MFMA16(a, b, c) __builtin_amdgcn_mfma_f32_16x16x32_bf16((a), (b), (c), 0, 0, 0)

static __device__ __forceinline__ float sigmoidf_(float x) {
    return 1.0f / (1.0f + __expf(-x));
}
// f32 -> bf16 round-to-nearest-even
static __device__ __forceinline__ unsigned short f2b(float f) {
    union { float f; unsigned int u; } v; v.f = f;
    unsigned int r = v.u + 0x7FFF + ((v.u >> 16) & 1);
    return (unsigned short)(r >> 16);
}
static __device__ __forceinline__ float dot4_(float4 a, float4 b) {
    return a.x * b.x + a.y * b.y + a.z * b.z + a.w * b.w;
}

// ---------------------------------------------------------------------------
// Prep: bf16 weights + fused LSTM weight W' and bias b'.
// blocks 0..511: W' row b and b'. blocks 512..575: convert Wn, Wg.
// ---------------------------------------------------------------------------
__global__ __launch_bounds__(256) void k_prep(
    const float* __restrict__ Wn, const float* __restrict__ Wg,
    const float* __restrict__ Wl, const float* __restrict__ bl,
    const float* __restrict__ Ws, const float* __restrict__ bs,
    unsigned short* __restrict__ WnB, unsigned short* __restrict__ WgB,
    unsigned short* __restrict__ WpB, float* __restrict__ bp)
{
    const int b = blockIdx.x, t = threadIdx.x;
    if (b < 512) {
        const float* wr = Wl + (size_t)b * CIN;
        unsigned short* out = WpB + (size_t)b * CIN2;
        for (int c = t; c < CIN2; c += 256) {
            float v;
            if (c < 288) v = wr[c];
            else if (c < 288 + SD) {
                int s = c - 288;
                float acc = 0.f;
                for (int j = 0; j < H; ++j) acc += wr[288 + j] * Ws[j * SD + s];
                v = acc;
            } else v = 0.f;
            out[c] = f2b(v);
        }
        if (t == 0) {
            float acc = bl[b];
            for (int j = 0; j < H; ++j) acc += wr[288 + j] * bs[j];
            bp[b] = acc;
        }
    } else {
        int idx = (b - 512) * 256 + t;  // 16384 threads
        for (int r = idx; r < 49152; r += 16384) {
            if (r < 16384) WnB[r] = f2b(Wn[r]);
            else WgB[r - 16384] = f2b(Wg[r - 16384]);
        }
    }
}

// ---------------------------------------------------------------------------
// Neighbor context via MFMA. 8 nodes/block, 256 threads (4 waves).
// Rows: 64 inflow rows (node*8+k) -> 4 M-tiles; 8 h_self rows -> 1 M-tile.
// Wave w owns h-cols [w*32, w*32+32) for msg, pregate, gh.
// ---------------------------------------------------------------------------
__global__ __launch_bounds__(256) void k_nb_mfma(
    const float* __restrict__ hself_g, const float* __restrict__ hin_g,
    const unsigned char* __restrict__ valid_raw,
    const unsigned short* __restrict__ WnB, const unsigned short* __restrict__ WgB,
    const float* __restrict__ bg,
    unsigned short* __restrict__ ncb, int nc_stride)
{
    __shared__ unsigned short hin_s[64 * 128];  // XOR-swizzled, 16KB
    __shared__ unsigned short hs_s[16 * 128];   // XOR-swizzled, 4KB (rows 8..15 unused)
    __shared__ float gh_s[8][128];              // 4KB
    __shared__ unsigned short ncs[8 * 128];     // 2KB
    __shared__ float valid_s[64];

    const int t = threadIdx.x;
    const int nb = blockIdx.x * 8;
    const int w = t >> 6, l = t & 63;
    const int ln = l & 15, lk = l >> 4;

    // valid mask staging with element-width detection (wave 0 only)
    if (t < 64) {
        int loc = 0;
        #pragma unroll
        for (int i = 0; i < 8; ++i) loc |= valid_raw[4 * (t * 8 + i) + 1];
        const int f8 = __any(loc != 0) ? 1 : 0;
        bool v = f8 ? (valid_raw[(size_t)nb * KI + t] != 0)
                    : (((const unsigned int*)valid_raw)[(size_t)nb * KI + t] != 0u);
        valid_s[t] = v ? 1.f : 0.f;
    }

    // stage h_inflows: 8192 f32 -> bf16 swizzled
    {
        const float4* src = (const float4*)(hin_g + (size_t)nb * KI * H);
        #pragma unroll
        for (int i = 0; i < 8; ++i) {
            int p4 = t + i * 256;
            float4 v = src[p4];
            int e = p4 * 4, row = e >> 7, col = e & 127;
            unsigned int byte = (unsigned)(row * 256 + col * 2) ^ (unsigned)((row & 7) << 4);
            us4 pk = { f2b(v.x), f2b(v.y), f2b(v.z), f2b(v.w) };
            *(us4*)((char*)hin_s + byte) = pk;
        }
    }
    // stage h_self: 1024 f32
    {
        const float4* src = (const float4*)(hself_g + (size_t)nb * H);
        float4 v = src[t];
        int e = t * 4, row = e >> 7, col = e & 127;
        unsigned int byte = (unsigned)(row * 256 + col * 2) ^ (unsigned)((row & 7) << 4);
        us4 pk = { f2b(v.x), f2b(v.y), f2b(v.z), f2b(v.w) };
        *(us4*)((char*)hs_s + byte) = pk;
    }
    __syncthreads();

    f32x4 accM[4][2], accP[4][2], accG[2];
    #pragma unroll
    for (int m = 0; m < 4; ++m)
        #pragma unroll
        for (int c = 0; c < 2; ++c) { accM[m][c] = (f32x4)0.f; accP[m][c] = (f32x4)0.f; }
    accG[0] = (f32x4)0.f; accG[1] = (f32x4)0.f;

    const int cbase = w * 32;
    #pragma unroll
    for (int kk = 0; kk < 4; ++kk) {
        const int k0 = kk * 32 + lk * 8;
        bf16x8 bn[2], ba[2], bb[2];
        #pragma unroll
        for (int c = 0; c < 2; ++c) {
            int col = cbase + c * 16 + ln;
            bn[c] = *(const bf16x8*)(WnB + col * H + k0);
            ba[c] = *(const bf16x8*)(WgB + col * 2 * H + k0);
            bb[c] = *(const bf16x8*)(WgB + col * 2 * H + H + k0);
        }
        bf16x8 am[4];
        #pragma unroll
        for (int m = 0; m < 4; ++m) {
            int row = m * 16 + ln;
            unsigned int byte = (unsigned)(row * 256 + k0 * 2) ^ (unsigned)((row & 7) << 4);
            am[m] = *(const bf16x8*)((const char*)hin_s + byte);
        }
        bf16x8 ah;
        {
            unsigned int byte = (unsigned)(ln * 256 + k0 * 2) ^ (unsigned)((ln & 7) << 4);
            ah = *(const bf16x8*)((const char*)hs_s + byte);
        }
        #pragma unroll
        for (int m = 0; m < 4; ++m)
            #pragma unroll
            for (int c = 0; c < 2; ++c) {
                accM[m][c] = MFMA16(am[m], bn[c], accM[m][c]);
                accP[m][c] = MFMA16(am[m], ba[c], accP[m][c]);
            }
        accG[0] = MFMA16(ah, bb[0], accG[0]);
        accG[1] = MFMA16(ah, bb[1], accG[1]);
    }

    // gh (Wg_b @ h_self) to LDS
    #pragma unroll
    for (int c = 0; c < 2; ++c)
        #pragma unroll
        for (int r = 0; r < 4; ++r) {
            int row = lk * 4 + r;
            if (row < 8) gh_s[row][cbase + c * 16 + ln] = accG[c][r];
        }
    __syncthreads();

    // combine: gate = sigmoid(pregate + gh + bg); sum over k of gate*msg*valid
    #pragma unroll
    for (int m = 0; m < 4; ++m) {
        const int node = 2 * m + (lk >> 1);  // all 4 regs of a lane share a node
        #pragma unroll
        for (int c = 0; c < 2; ++c) {
            const int col = cbase + c * 16 + ln;
            const float bgc = bg[col];
            const float ghv = gh_s[node][col];
            float sum = 0.f;
            #pragma unroll
            for (int r = 0; r < 4; ++r) {
                int row = m * 16 + lk * 4 + r;
                float g = sigmoidf_(accP[m][c][r] + ghv + bgc);
                sum += valid_s[row] * g * accM[m][c][r];
            }
            sum += __shfl_xor(sum, 16);
            if ((l & 16) == 0) ncs[(2 * m + (l >> 5)) * H + col] = f2b(sum);
        }
    }
    __syncthreads();

    // coalesced bf16 write of nc
    {
        int e = t * 4, node = e >> 7, col = e & 127;
        us4 v = *(const us4*)(ncs + e);
        *(us4*)(ncb + (size_t)(nb + node) * nc_stride + col) = v;
    }
}

// ---------------------------------------------------------------------------
// LSTM via MFMA. 16 nodes/block, 256 threads (4 waves).
// comb' bf16 [16][328] in LDS; wave w owns h-cols [w*32,w*32+32) of all 4 gates.
// ---------------------------------------------------------------------------
__global__ __launch_bounds__(256) void k_lstm_mfma(
    const float* __restrict__ x_g, const float* __restrict__ hself_g,
    const float* __restrict__ cself_g, const float* __restrict__ stat_g,
    const unsigned short* __restrict__ ncb, int nc_stride,
    const unsigned short* __restrict__ WpB, const float* __restrict__ bp,
    const float* __restrict__ lnw, const float* __restrict__ lnb,
    float* __restrict__ h_out, float* __restrict__ c_out)
{
    __shared__ unsigned short comb[16 * CPAD];  // 10.25KB
    __shared__ float hpre[16][132];             // 8.25KB
    const int t = threadIdx.x;
    const int nb = blockIdx.x * 16;
    const int w = t >> 6, l = t & 63, ln = l & 15, lk = l >> 4;

    // ---- stage comb' = [x | h_self | nc | static | 0] as bf16 ----
    if (t < 128) {  // x: 512 f32
        float4 v = ((const float4*)(x_g + (size_t)nb * XD))[t];
        int e = t * 4, row = e >> 5, col = e & 31;
        us4 pk = { f2b(v.x), f2b(v.y), f2b(v.z), f2b(v.w) };
        *(us4*)(comb + row * CPAD + col) = pk;
    }
    #pragma unroll
    for (int i = 0; i < 2; ++i) {  // h_self: 2048 f32
        int p4 = t + i * 256;
        float4 v = ((const float4*)(hself_g + (size_t)nb * H))[p4];
        int e = p4 * 4, row = e >> 7, col = 32 + (e & 127);
        us4 pk = { f2b(v.x), f2b(v.y), f2b(v.z), f2b(v.w) };
        *(us4*)(comb + row * CPAD + col) = pk;
    }
    #pragma unroll
    for (int i = 0; i < 2; ++i) {  // nc: 2048 bf16 (already bf16)
        int p4 = t + i * 256;
        int e = p4 * 4, row = e >> 7, col = e & 127;
        us4 v = *(const us4*)(ncb + (size_t)(nb + row) * nc_stride + col);
        *(us4*)(comb + row * CPAD + 160 + col) = v;
    }
    for (int i = t; i < 16 * SD; i += 256) {  // static: 432 f32, scalar
        int row = i / SD, col = i - row * SD;
        comb[row * CPAD + 288 + col] = f2b(stat_g[(size_t)(nb + row) * SD + col]);
    }
    for (int i = t; i < 16 * (CPAD - 315); i += 256) {  // zero cols 315..327
        int nz = CPAD - 315;
        int row = i / nz, col = 315 + (i - row * nz);
        comb[row * CPAD + col] = 0;
    }
    __syncthreads();

    // ---- GEMM: z[16 x 512] = comb' @ W'^T ----
    f32x4 acc[4][2];
    #pragma unroll
    for (int g = 0; g < 4; ++g) { acc[g][0] = (f32x4)0.f; acc[g][1] = (f32x4)0.f; }

    #pragma unroll
    for (int kk = 0; kk < 10; ++kk) {
        const int k0 = kk * 32 + lk * 8;
        bf16x8 a = *(const bf16x8*)(comb + ln * CPAD + k0);
        #pragma unroll
        for (int g = 0; g < 4; ++g)
            #pragma unroll
            for (int p = 0; p < 2; ++p) {
                int zr = g * H + w * 32 + p * 16 + ln;
                bf16x8 b = *(const bf16x8*)(WpB + (size_t)zr * CIN2 + k0);
                acc[g][p] = MFMA16(a, b, acc[g][p]);
            }
    }

    // ---- LSTM elementwise (in-register) ----
    #pragma unroll
    for (int p = 0; p < 2; ++p) {
        const int h = w * 32 + p * 16 + ln;
        const float bi = bp[h], bf = bp[H + h], bo = bp[2 * H + h], bgg = bp[3 * H + h];
        #pragma unroll
        for (int r = 0; r < 4; ++r) {
            int node = lk * 4 + r;
            size_t n = (size_t)(nb + node);
            float zi = acc[0][p][r] + bi;
            float zf = acc[1][p][r] + bf;
            float zo = acc[2][p][r] + bo;
            float zg = acc[3][p][r] + bgg;
            float cn = sigmoidf_(zf) * cself_g[n * H + h] + sigmoidf_(zi) * tanhf(zg);
            c_out[n * H + h] = cn;
            hpre[node][h] = sigmoidf_(zo) * tanhf(cn);
        }
    }
    __syncthreads();

    // ---- LayerNorm over H=128, 4 nodes per wave ----
    #pragma unroll
    for (int jj = 0; jj < 4; ++jj) {
        const int j = w * 4 + jj;
        const size_t n = (size_t)(nb + j);
        float a = hpre[j][l];
        float b = hpre[j][64 + l];
        float s = a + b, q = a * a + b * b;
        #pragma unroll
        for (int off = 1; off < 64; off <<= 1) {
            s += __shfl_xor(s, off);
            q += __shfl_xor(q, off);
        }
        float mu = s * (1.0f / 128.0f);
        float var = q * (1.0f / 128.0f) - mu * mu;
        float rstd = rsqrtf(var + 1e-5f);
        h_out[n * H + l]      = (a - mu) * rstd * lnw[l] + lnb[l];
        h_out[n * H + 64 + l] = (b - mu) * rstd * lnw[64 + l] + lnb[64 + l];
    }
}

// ---------------------------------------------------------------------------
// f32 fallback path (round-0 kernels) — used only if ws is too small.
// ---------------------------------------------------------------------------
__global__ __launch_bounds__(256) void k_nb_f32(
    const float* __restrict__ hself_g, const float* __restrict__ hin_g,
    const unsigned char* __restrict__ valid_raw,
    const float* __restrict__ Wn, const float* __restrict__ Wg,
    const float* __restrict__ bg, float* __restrict__ nc)
{
    __shared__ float4 hin_s[8 * KI * (H / 4)];
    __shared__ float4 hs_s[8 * (H / 4)];
    __shared__ int flag8;
    const int t = threadIdx.x;
    const int nb = blockIdx.x * 8;
    {
        int loc = 0;
        if (t < 64) {
            #pragma unroll
            for (int i = 0; i < 16; ++i) loc |= valid_raw[4 * (t * 16 + i) + 1];
        }
        int any = __any(loc != 0);
        if (t == 0) flag8 = any;
    }
    const float4* src_hin = (const float4*)(hin_g + (size_t)nb * KI * H);
    #pragma unroll
    for (int i = 0; i < 8; ++i) hin_s[t + i * 256] = src_hin[t + i * 256];
    hs_s[t] = ((const float4*)(hself_g + (size_t)nb * H))[t];
    __syncthreads();
    const int o = t & 127, g = t >> 7;
    float msg[4][KI], gat[4][KI], gh[4];
    #pragma unroll
    for (int j = 0; j < 4; ++j) {
        gh[j] = 0.f;
        #pragma unroll
        for (int k = 0; k < KI; ++k) { msg[j][k] = 0.f; gat[j][k] = 0.f; }
    }
    const float4* Wn4 = (const float4*)(Wn + (size_t)o * H);
    const float4* Wg4a = (const float4*)(Wg + (size_t)o * 2 * H);
    const float4* Wg4b = (const float4*)(Wg + (size_t)o * 2 * H + H);
    for (int d4 = 0; d4 < H / 4; ++d4) {
        float4 wn = Wn4[d4], w0 = Wg4a[d4], w1 = Wg4b[d4];
        #pragma unroll
        for (int j = 0; j < 4; ++j) {
            const int node = g * 4 + j;
            gh[j] += dot4_(w1, hs_s[node * 32 + d4]);
            #pragma unroll
            for (int k = 0; k < KI; ++k) {
                float4 hv = hin_s[(node * KI + k) * 32 + d4];
                msg[j][k] += dot4_(wn, hv);
                gat[j][k] += dot4_(w0, hv);
            }
        }
    }
    const float bgo = bg[o];
    const unsigned int* valid32 = (const unsigned int*)valid_raw;
    const int f8 = flag8;
    #pragma unroll
    for (int j = 0; j < 4; ++j) {
        const int n = nb + g * 4 + j;
        float acc = 0.f;
        #pragma unroll
        for (int k = 0; k < KI; ++k) {
            bool v = f8 ? (valid_raw[n * KI + k] != 0) : (valid32[n * KI + k] != 0u);
            if (v) acc += sigmoidf_(gat[j][k] + gh[j] + bgo) * msg[j][k];
        }
        nc[(size_t)n * H + o] = acc;
    }
}

__global__ __launch_bounds__(256) void k_lstm_f32(
    const float* __restrict__ x_g, const float* __restrict__ hself_g,
    const float* __restrict__ cself_g, const float* __restrict__ stat_g,
    const float* __restrict__ nc,
    const float* __restrict__ Ws, const float* __restrict__ bs,
    const float* __restrict__ Wl, const float* __restrict__ bl,
    const float* __restrict__ lnw, const float* __restrict__ lnb,
    float* __restrict__ h_out, float* __restrict__ c_out)
{
    __shared__ float4 comb4[16 * (CIN / 4)];
    __shared__ float zsh[16 * ZOUT];
    __shared__ float stat_s[16 * SD];
    float* combf = (float*)comb4;
    const int t = threadIdx.x;
    const int nb = blockIdx.x * 16;
    #pragma unroll
    for (int i = 0; i < 2; ++i) {
        int idx = t + i * 256;
        combf[(idx >> 5) * CIN + (idx & 31)] = x_g[(size_t)nb * XD + idx];
    }
    #pragma unroll
    for (int i = 0; i < 8; ++i) {
        int idx = t + i * 256;
        combf[(idx >> 7) * CIN + 32 + (idx & 127)] = hself_g[(size_t)nb * H + idx];
    }
    #pragma unroll
    for (int i = 0; i < 8; ++i) {
        int idx = t + i * 256;
        combf[(idx >> 7) * CIN + 160 + (idx & 127)] = nc[(size_t)nb * H + idx];
    }
    stat_s[t] = stat_g[(size_t)nb * SD + t];
    if (t < 16 * SD - 256) stat_s[t + 256] = stat_g[(size_t)nb * SD + t + 256];
    __syncthreads();
    {
        const int o = t & 127, jg = t >> 7;
        #pragma unroll
        for (int jj = 0; jj < 8; ++jj) {
            const int j = jg * 8 + jj;
            float s = bs[o];
            #pragma unroll
            for (int c = 0; c < SD; ++c) s += Ws[o * SD + c] * stat_s[j * SD + c];
            combf[j * CIN + 288 + o] = s;
        }
    }
    __syncthreads();
    float acc0[16], acc1[16];
    #pragma unroll
    for (int j = 0; j < 16; ++j) { acc0[j] = 0.f; acc1[j] = 0.f; }
    const float4* W0 = (const float4*)(Wl + (size_t)t * CIN);
    const float4* W1 = (const float4*)(Wl + (size_t)(t + 256) * CIN);
    for (int d4 = 0; d4 < CIN / 4; ++d4) {
        float4 w0 = W0[d4], w1 = W1[d4];
        #pragma unroll
        for (int j = 0; j < 16; ++j) {
            float4 cv = comb4[j * (CIN / 4) + d4];
            acc0[j] += dot4_(w0, cv);
            acc1[j] += dot4_(w1, cv);
        }
    }
    const float bl0 = bl[t], bl1 = bl[t + 256];
    #pragma unroll
    for (int j = 0; j < 16; ++j) {
        zsh[j * ZOUT + t] = acc0[j] + bl0;
        zsh[j * ZOUT + 256 + t] = acc1[j] + bl1;
    }
    __syncthreads();
    {
        const int h = t & 127, jg = t >> 7;
        #pragma unroll
        for (int jj = 0; jj < 8; ++jj) {
            const int j = jg * 8 + jj;
            const size_t n = (size_t)(nb + j);
            float zi = zsh[j * ZOUT + h];
            float zf = zsh[j * ZOUT + 128 + h];
            float zo = zsh[j * ZOUT + 256 + h];
            float zg = zsh[j * ZOUT + 384 + h];
            float cn = sigmoidf_(zf) * cself_g[n * H + h] + sigmoidf_(zi) * tanhf(zg);
            c_out[n * H + h] = cn;
            zsh[j * ZOUT + h] = sigmoidf_(zo) * tanhf(cn);
        }
    }
    __syncthreads();
    {
        const int w = t >> 6, lane = t & 63;
        #pragma unroll
        for (int jj = 0; jj < 4; ++jj) {
            const int j = w * 4 + jj;
            const size_t n = (size_t)(nb + j);
            float a = zsh[j * ZOUT + lane];
            float b = zsh[j * ZOUT + 64 + lane];
            float s = a + b, q = a * a + b * b;
            #pragma unroll
            for (int off = 1; off < 64; off <<= 1) {
                s += __shfl_xor(s, off);
                q += __shfl_xor(q, off);
            }
            float mu = s * (1.0f / 128.0f);
            float var = q * (1.0f / 128.0f) - mu * mu;
            float rstd = rsqrtf(var + 1e-5f);
            h_out[n * H + lane] = (a - mu) * rstd * lnw[lane] + lnb[lane];
            h_out[n * H + 64 + lane] = (b - mu) * rstd * lnw[64 + lane] + lnb[64 + lane];
        }
    }
}

extern "C" void kernel_launch(void* const* d_in, const int* in_sizes, int n_in,
                              void* d_out, int out_size, void* d_ws, size_t ws_size,
                              hipStream_t stream) {
    const float* x      = (const float*)d_in[0];
    const float* h_self = (const float*)d_in[1];
    const float* c_self = (const float*)d_in[2];
    const float* h_inf  = (const float*)d_in[3];
    const unsigned char* valid = (const unsigned char*)d_in[4];
    const float* statp  = (const float*)d_in[5];
    const float* Wn     = (const float*)d_in[6];
    const float* Wg     = (const float*)d_in[7];
    const float* bg     = (const float*)d_in[8];
    const float* Ws     = (const float*)d_in[9];
    const float* bs     = (const float*)d_in[10];
    const float* Wl     = (const float*)d_in[11];
    const float* bl     = (const float*)d_in[12];
    const float* lnw    = (const float*)d_in[13];
    const float* lnb    = (const float*)d_in[14];

    float* h_out = (float*)d_out;
    float* c_out = h_out + (size_t)NN * H;

    // ws layout: W'(327680B) | WnB(32768B) | WgB(65536B) | bp(2048B) | nc
    const size_t W_BYTES = (size_t)512 * CIN2 * 2 + 16384 * 2 + 32768 * 2 + 512 * 4;
    const size_t NC_BYTES = (size_t)NN * H * 2;

    if (ws_size >= W_BYTES) {
        char* p = (char*)d_ws;
        unsigned short* WpB = (unsigned short*)p;           p += (size_t)512 * CIN2 * 2;
        unsigned short* WnB = (unsigned short*)p;           p += 16384 * 2;
        unsigned short* WgB = (unsigned short*)p;           p += 32768 * 2;
        float* bp = (float*)p;                              p += 512 * 4;

        unsigned short* ncb;
        int nc_stride;
        if (ws_size >= W_BYTES + NC_BYTES + 64) {
            ncb = (unsigned short*)p;   // compact nc in ws
            nc_stride = H;
        } else {
            // block-local overlay inside h_out: row n occupies first 256B of
            // h_out row n (512B); k_lstm reads only its own rows before writing.
            ncb = (unsigned short*)h_out;
            nc_stride = 256;
        }

        k_prep<<<576, 256, 0, stream>>>(Wn, Wg, Wl, bl, Ws, bs,
                                        WnB, WgB, WpB, bp);
        k_nb_mfma<<<NN / 8, 256, 0, stream>>>(h_self, h_inf, valid, WnB, WgB, bg,
                                              ncb, nc_stride);
        k_lstm_mfma<<<NN / 16, 256, 0, stream>>>(x, h_self, c_self, statp,
                                                 ncb, nc_stride, WpB, bp,
                                                 lnw, lnb, h_out, c_out);
    } else {
        // tiny-ws fallback: f32 path, nc in h_out (block-local reads)
        float* nc_buf = (ws_size >= (size_t)NN * H * sizeof(float))
                            ? (float*)d_ws : h_out;
        k_nb_f32<<<NN / 8, 256, 0, stream>>>(h_self, h_inf, valid, Wn, Wg, bg, nc_buf);
        k_lstm_f32<<<NN / 16, 256, 0, stream>>>(x, h_self, c_self, statp, nc_buf,
                                                Ws, bs, Wl, bl, lnw, lnb, h_out, c_out);
    }
}

// Round 3
// 191.987 us; speedup vs baseline: 7.7476x; 1.3803x over previous
//
#include <hip/hip_runtime.h>
#include <hip/hip_bf16.h>

#define NN 50000
#define KI 8
#define H 128
#define XD 32
#define SD 27
#define CIN 416      // original combined width
#define CIN2 320     // fused combined: x(32)|h(128)|nc(128)|static(27)|pad(5)
#define CPAD 328     // LDS row stride (shorts)
#define ZOUT 512
#define NTILE_NB (NN / KI)   // 6250 tiles of 8 nodes
#define MB_LSTM 64           // nodes per k_lstm block

typedef __attribute__((ext_vector_type(8))) short bf16x8;
typedef __attribute__((ext_vector_type(4))) float f32x4;
typedef __attribute__((ext_vector_type(4))) unsigned short us4;

#define MFMA16(a, b, c) __builtin_amdgcn_mfma_f32_16x16x32_bf16((a), (b), (c), 0, 0, 0)

static __device__ __forceinline__ float sigmoidf_(float x) {
    return 1.0f / (1.0f + __expf(-x));
}
static __device__ __forceinline__ unsigned short f2b(float f) {
    union { float f; unsigned int u; } v; v.f = f;
    unsigned int r = v.u + 0x7FFF + ((v.u >> 16) & 1);
    return (unsigned short)(r >> 16);
}
static __device__ __forceinline__ float dot4_(float4 a, float4 b) {
    return a.x * b.x + a.y * b.y + a.z * b.z + a.w * b.w;
}

// ---------------------------------------------------------------------------
// Prep: bf16 weights + fused LSTM weight W' and bias b'.
// ---------------------------------------------------------------------------
__global__ __launch_bounds__(256) void k_prep(
    const float* __restrict__ Wn, const float* __restrict__ Wg,
    const float* __restrict__ Wl, const float* __restrict__ bl,
    const float* __restrict__ Ws, const float* __restrict__ bs,
    unsigned short* __restrict__ WnB, unsigned short* __restrict__ WgB,
    unsigned short* __restrict__ WpB, float* __restrict__ bp)
{
    const int b = blockIdx.x, t = threadIdx.x;
    if (b < 512) {
        const float* wr = Wl + (size_t)b * CIN;
        unsigned short* out = WpB + (size_t)b * CIN2;
        for (int c = t; c < CIN2; c += 256) {
            float v;
            if (c < 288) v = wr[c];
            else if (c < 288 + SD) {
                int s = c - 288;
                float acc = 0.f;
                for (int j = 0; j < H; ++j) acc += wr[288 + j] * Ws[j * SD + s];
                v = acc;
            } else v = 0.f;
            out[c] = f2b(v);
        }
        if (t == 0) {
            float acc = bl[b];
            for (int j = 0; j < H; ++j) acc += wr[288 + j] * bs[j];
            bp[b] = acc;
        }
    } else {
        int idx = (b - 512) * 256 + t;
        for (int r = idx; r < 49152; r += 16384) {
            if (r < 16384) WnB[r] = f2b(Wn[r]);
            else WgB[r - 16384] = f2b(Wg[r - 16384]);
        }
    }
}

// ---------------------------------------------------------------------------
// Neighbor context: persistent weight registers, grid-stride over 8-node tiles.
// 256 threads (4 waves); wave w owns h-cols [w*32, w*32+32).
// ---------------------------------------------------------------------------
__global__ __launch_bounds__(256, 2) void k_nb_mfma(
    const float* __restrict__ hself_g, const float* __restrict__ hin_g,
    const unsigned char* __restrict__ valid_raw,
    const unsigned short* __restrict__ WnB, const unsigned short* __restrict__ WgB,
    const float* __restrict__ bg,
    unsigned short* __restrict__ ncb, int nc_stride)
{
    __shared__ unsigned short hin_s[64 * 128];  // XOR-swizzled, 16KB
    __shared__ unsigned short hs_s[8 * 128];    // XOR-swizzled, 2KB
    __shared__ float gh_s[8][128];              // 4KB
    __shared__ unsigned short ncs[8 * 128];     // 2KB
    __shared__ float valid_s[64];

    const int t = threadIdx.x;
    const int w = t >> 6, l = t & 63;
    const int ln = l & 15, lk = l >> 4;

    // detect inflow_valid element width (bool8 vs 4-byte) — uniform, once
    int det = 0;
    #pragma unroll
    for (int i = 0; i < 64; ++i) det |= valid_raw[4 * i + 1];
    const bool f8 = (det != 0);

    // ---- persistent B fragments: Wn, Wg_a (inflow), Wg_b (h_self) ----
    bf16x8 Bn[2][4], Ba[2][4], Bb[2][4];
    const int cbase = w * 32;
    #pragma unroll
    for (int c = 0; c < 2; ++c) {
        const int col = cbase + c * 16 + ln;
        #pragma unroll
        for (int kk = 0; kk < 4; ++kk) {
            const int k0 = kk * 32 + lk * 8;
            Bn[c][kk] = *(const bf16x8*)(WnB + col * H + k0);
            Ba[c][kk] = *(const bf16x8*)(WgB + col * 2 * H + k0);
            Bb[c][kk] = *(const bf16x8*)(WgB + col * 2 * H + H + k0);
        }
    }
    const float bg0 = bg[cbase + ln];
    const float bg1 = bg[cbase + 16 + ln];

    for (int tile = blockIdx.x; tile < NTILE_NB; tile += gridDim.x) {
        const int nb = tile * 8;

        if (t < 64) {
            bool v = f8 ? (valid_raw[(size_t)nb * KI + t] != 0)
                        : (((const unsigned int*)valid_raw)[(size_t)nb * KI + t] != 0u);
            valid_s[t] = v ? 1.f : 0.f;
        }
        // ---- stage h_inflows (32KB f32) + h_self (8 rows) as swizzled bf16 ----
        {
            const float4* src = (const float4*)(hin_g + (size_t)nb * KI * H);
            float4 r0[8];
            #pragma unroll
            for (int i = 0; i < 8; ++i) r0[i] = src[t + i * 256];
            float4 hv = ((const float4*)(hself_g + (size_t)nb * H))[t];
            #pragma unroll
            for (int i = 0; i < 8; ++i) {
                int e = (t + i * 256) * 4, row = e >> 7, col = e & 127;
                unsigned byte = (unsigned)(row * 256 + col * 2) ^ (unsigned)((row & 7) << 4);
                us4 pk = { f2b(r0[i].x), f2b(r0[i].y), f2b(r0[i].z), f2b(r0[i].w) };
                *(us4*)((char*)hin_s + byte) = pk;
            }
            {
                int e = t * 4, row = e >> 7, col = e & 127;  // rows 0..7
                unsigned byte = (unsigned)(row * 256 + col * 2) ^ (unsigned)((row & 7) << 4);
                us4 pk = { f2b(hv.x), f2b(hv.y), f2b(hv.z), f2b(hv.w) };
                *(us4*)((char*)hs_s + byte) = pk;
            }
        }
        __syncthreads();

        // ---- MFMA: msgs, pregates, gh (B from registers) ----
        f32x4 accM[4][2], accP[4][2], accG[2];
        #pragma unroll
        for (int m = 0; m < 4; ++m)
            #pragma unroll
            for (int c = 0; c < 2; ++c) { accM[m][c] = (f32x4)0.f; accP[m][c] = (f32x4)0.f; }
        accG[0] = (f32x4)0.f; accG[1] = (f32x4)0.f;

        #pragma unroll
        for (int kk = 0; kk < 4; ++kk) {
            const int k0 = kk * 32 + lk * 8;
            bf16x8 am[4];
            #pragma unroll
            for (int m = 0; m < 4; ++m) {
                int row = m * 16 + ln;
                unsigned byte = (unsigned)(row * 256 + k0 * 2) ^ (unsigned)((row & 7) << 4);
                am[m] = *(const bf16x8*)((const char*)hin_s + byte);
            }
            bf16x8 ah;
            {
                int row = ln & 7;
                unsigned byte = (unsigned)(row * 256 + k0 * 2) ^ (unsigned)((row & 7) << 4);
                ah = *(const bf16x8*)((const char*)hs_s + byte);
            }
            #pragma unroll
            for (int m = 0; m < 4; ++m)
                #pragma unroll
                for (int c = 0; c < 2; ++c) {
                    accM[m][c] = MFMA16(am[m], Bn[c][kk], accM[m][c]);
                    accP[m][c] = MFMA16(am[m], Ba[c][kk], accP[m][c]);
                }
            accG[0] = MFMA16(ah, Bb[0][kk], accG[0]);
            accG[1] = MFMA16(ah, Bb[1][kk], accG[1]);
        }

        #pragma unroll
        for (int c = 0; c < 2; ++c)
            #pragma unroll
            for (int r = 0; r < 4; ++r) {
                int row = lk * 4 + r;
                if (row < 8) gh_s[row][cbase + c * 16 + ln] = accG[c][r];
            }
        __syncthreads();

        // ---- epilogue: sigmoid gate, mask, k-sum, stage nc ----
        #pragma unroll
        for (int m = 0; m < 4; ++m) {
            const int node = 2 * m + (lk >> 1);
            #pragma unroll
            for (int c = 0; c < 2; ++c) {
                const int col = cbase + c * 16 + ln;
                const float bgc = c ? bg1 : bg0;
                const float ghv = gh_s[node][col];
                float sum = 0.f;
                #pragma unroll
                for (int r = 0; r < 4; ++r) {
                    int row = m * 16 + lk * 4 + r;
                    float g = sigmoidf_(accP[m][c][r] + ghv + bgc);
                    sum += valid_s[row] * g * accM[m][c][r];
                }
                sum += __shfl_xor(sum, 16);
                if ((l & 16) == 0) ncs[(2 * m + (l >> 5)) * H + col] = f2b(sum);
            }
        }
        __syncthreads();

        {   // coalesced bf16 nc write
            int e = t * 4, node = e >> 7, col = e & 127;
            us4 v = *(const us4*)(ncs + e);
            *(us4*)(ncb + (size_t)(nb + node) * nc_stride + col) = v;
        }
        __syncthreads();
    }
}

// ---------------------------------------------------------------------------
// LSTM via MFMA. 64 nodes/block, 256 threads (4 waves).
// Wave w owns h-cols [w*32,w*32+32) of all 4 gates; 4 M-tiles of 16 nodes.
// ---------------------------------------------------------------------------
__global__ __launch_bounds__(256, 2) void k_lstm_mfma(
    const float* __restrict__ x_g, const float* __restrict__ hself_g,
    const float* __restrict__ cself_g, const float* __restrict__ stat_g,
    const unsigned short* __restrict__ ncb, int nc_stride,
    const unsigned short* __restrict__ WpB, const float* __restrict__ bp,
    const float* __restrict__ lnw, const float* __restrict__ lnb,
    float* __restrict__ h_out, float* __restrict__ c_out)
{
    __shared__ char smem[MB_LSTM * CPAD * 2];               // 42KB
    unsigned short* comb = (unsigned short*)smem;           // [64][328] bf16
    float (*hpre)[132] = (float(*)[132])smem;               // union, after GEMM

    const int t = threadIdx.x;
    const int nb = blockIdx.x * MB_LSTM;
    const int w = t >> 6, l = t & 63, ln = l & 15, lk = l >> 4;

    // ---- stage comb' = [x | h_self | nc | static | 0] as bf16 (guarded) ----
    #pragma unroll
    for (int i = 0; i < 2; ++i) {  // x: 64*32 f32 = 512 float4
        int p4 = t + i * 256;
        int e = p4 * 4, row = e >> 5, col = e & 31;
        us4 pk = { 0, 0, 0, 0 };
        if (nb + row < NN) {
            float4 v = ((const float4*)(x_g + (size_t)nb * XD))[p4];
            pk = us4{ f2b(v.x), f2b(v.y), f2b(v.z), f2b(v.w) };
        }
        *(us4*)(comb + row * CPAD + col) = pk;
    }
    #pragma unroll
    for (int i = 0; i < 8; ++i) {  // h_self: 64*128 f32 = 2048 float4
        int p4 = t + i * 256;
        int e = p4 * 4, row = e >> 7, col = 32 + (e & 127);
        us4 pk = { 0, 0, 0, 0 };
        if (nb + row < NN) {
            float4 v = ((const float4*)(hself_g + (size_t)nb * H))[p4];
            pk = us4{ f2b(v.x), f2b(v.y), f2b(v.z), f2b(v.w) };
        }
        *(us4*)(comb + row * CPAD + col) = pk;
    }
    #pragma unroll
    for (int i = 0; i < 8; ++i) {  // nc: 64*128 bf16 = 2048 us4
        int p4 = t + i * 256;
        int e = p4 * 4, row = e >> 7, col = e & 127;
        us4 v = { 0, 0, 0, 0 };
        if (nb + row < NN) v = *(const us4*)(ncb + (size_t)(nb + row) * nc_stride + col);
        *(us4*)(comb + row * CPAD + 160 + col) = v;
    }
    for (int i = t; i < MB_LSTM * SD; i += 256) {  // static: 64*27 f32
        int row = i / SD, col = i - row * SD;
        unsigned short v = 0;
        if (nb + row < NN) v = f2b(stat_g[(size_t)(nb + row) * SD + col]);
        comb[row * CPAD + 288 + col] = v;
    }
    for (int i = t; i < MB_LSTM * (CPAD - 315); i += 256) {  // zero 315..327
        int nz = CPAD - 315;
        int row = i / nz, col = 315 + (i - row * nz);
        comb[row * CPAD + col] = 0;
    }
    __syncthreads();

    // ---- GEMM: z[64 x 512] = comb' @ W'^T ----
    f32x4 acc[4][4][2];  // [m-tile][gate][p]
    #pragma unroll
    for (int m = 0; m < 4; ++m)
        #pragma unroll
        for (int g = 0; g < 4; ++g) { acc[m][g][0] = (f32x4)0.f; acc[m][g][1] = (f32x4)0.f; }

    #pragma unroll
    for (int kk = 0; kk < 10; ++kk) {
        const int k0 = kk * 32 + lk * 8;
        bf16x8 a[4];
        #pragma unroll
        for (int m = 0; m < 4; ++m)
            a[m] = *(const bf16x8*)(comb + (m * 16 + ln) * CPAD + k0);
        #pragma unroll
        for (int g = 0; g < 4; ++g)
            #pragma unroll
            for (int p = 0; p < 2; ++p) {
                int zr = g * H + w * 32 + p * 16 + ln;
                bf16x8 b = *(const bf16x8*)(WpB + (size_t)zr * CIN2 + k0);
                #pragma unroll
                for (int m = 0; m < 4; ++m)
                    acc[m][g][p] = MFMA16(a[m], b, acc[m][g][p]);
            }
    }
    __syncthreads();  // comb reads done; hpre may overwrite

    // ---- LSTM elementwise (in-register) ----
    #pragma unroll
    for (int p = 0; p < 2; ++p) {
        const int h = w * 32 + p * 16 + ln;
        const float bi = bp[h], bf = bp[H + h], bo = bp[2 * H + h], bgg = bp[3 * H + h];
        #pragma unroll
        for (int m = 0; m < 4; ++m)
            #pragma unroll
            for (int r = 0; r < 4; ++r) {
                int node = m * 16 + lk * 4 + r;
                size_t n = (size_t)(nb + node);
                if (n < NN) {
                    float zi = acc[m][0][p][r] + bi;
                    float zf = acc[m][1][p][r] + bf;
                    float zo = acc[m][2][p][r] + bo;
                    float zg = acc[m][3][p][r] + bgg;
                    float cn = sigmoidf_(zf) * cself_g[n * H + h] + sigmoidf_(zi) * tanhf(zg);
                    c_out[n * H + h] = cn;
                    hpre[node][h] = sigmoidf_(zo) * tanhf(cn);
                }
            }
    }
    __syncthreads();

    // ---- LayerNorm over H=128, 16 nodes per wave ----
    #pragma unroll
    for (int jj = 0; jj < 16; ++jj) {
        const int j = w * 16 + jj;
        const size_t n = (size_t)(nb + j);
        if (n < NN) {
            float a = hpre[j][l];
            float b = hpre[j][64 + l];
            float s = a + b, q = a * a + b * b;
            #pragma unroll
            for (int off = 1; off < 64; off <<= 1) {
                s += __shfl_xor(s, off);
                q += __shfl_xor(q, off);
            }
            float mu = s * (1.0f / 128.0f);
            float var = q * (1.0f / 128.0f) - mu * mu;
            float rstd = rsqrtf(var + 1e-5f);
            h_out[n * H + l]      = (a - mu) * rstd * lnw[l] + lnb[l];
            h_out[n * H + 64 + l] = (b - mu) * rstd * lnw[64 + l] + lnb[64 + l];
        }
    }
}

// ---------------------------------------------------------------------------
// f32 fallback path — used only if ws is too small.
// ---------------------------------------------------------------------------
__global__ __launch_bounds__(256) void k_nb_f32(
    const float* __restrict__ hself_g, const float* __restrict__ hin_g,
    const unsigned char* __restrict__ valid_raw,
    const float* __restrict__ Wn, const float* __restrict__ Wg,
    const float* __restrict__ bg, float* __restrict__ nc)
{
    __shared__ float4 hin_s[8 * KI * (H / 4)];
    __shared__ float4 hs_s[8 * (H / 4)];
    __shared__ int flag8;
    const int t = threadIdx.x;
    const int nb = blockIdx.x * 8;
    {
        int loc = 0;
        if (t < 64) {
            #pragma unroll
            for (int i = 0; i < 16; ++i) loc |= valid_raw[4 * (t * 16 + i) + 1];
        }
        int any = __any(loc != 0);
        if (t == 0) flag8 = any;
    }
    const float4* src_hin = (const float4*)(hin_g + (size_t)nb * KI * H);
    #pragma unroll
    for (int i = 0; i < 8; ++i) hin_s[t + i * 256] = src_hin[t + i * 256];
    hs_s[t] = ((const float4*)(hself_g + (size_t)nb * H))[t];
    __syncthreads();
    const int o = t & 127, g = t >> 7;
    float msg[4][KI], gat[4][KI], gh[4];
    #pragma unroll
    for (int j = 0; j < 4; ++j) {
        gh[j] = 0.f;
        #pragma unroll
        for (int k = 0; k < KI; ++k) { msg[j][k] = 0.f; gat[j][k] = 0.f; }
    }
    const float4* Wn4 = (const float4*)(Wn + (size_t)o * H);
    const float4* Wg4a = (const float4*)(Wg + (size_t)o * 2 * H);
    const float4* Wg4b = (const float4*)(Wg + (size_t)o * 2 * H + H);
    for (int d4 = 0; d4 < H / 4; ++d4) {
        float4 wn = Wn4[d4], w0 = Wg4a[d4], w1 = Wg4b[d4];
        #pragma unroll
        for (int j = 0; j < 4; ++j) {
            const int node = g * 4 + j;
            gh[j] += dot4_(w1, hs_s[node * 32 + d4]);
            #pragma unroll
            for (int k = 0; k < KI; ++k) {
                float4 hv = hin_s[(node * KI + k) * 32 + d4];
                msg[j][k] += dot4_(wn, hv);
                gat[j][k] += dot4_(w0, hv);
            }
        }
    }
    const float bgo = bg[o];
    const unsigned int* valid32 = (const unsigned int*)valid_raw;
    const int f8 = flag8;
    #pragma unroll
    for (int j = 0; j < 4; ++j) {
        const int n = nb + g * 4 + j;
        float acc = 0.f;
        #pragma unroll
        for (int k = 0; k < KI; ++k) {
            bool v = f8 ? (valid_raw[n * KI + k] != 0) : (valid32[n * KI + k] != 0u);
            if (v) acc += sigmoidf_(gat[j][k] + gh[j] + bgo) * msg[j][k];
        }
        nc[(size_t)n * H + o] = acc;
    }
}

__global__ __launch_bounds__(256) void k_lstm_f32(
    const float* __restrict__ x_g, const float* __restrict__ hself_g,
    const float* __restrict__ cself_g, const float* __restrict__ stat_g,
    const float* __restrict__ nc,
    const float* __restrict__ Ws, const float* __restrict__ bs,
    const float* __restrict__ Wl, const float* __restrict__ bl,
    const float* __restrict__ lnw, const float* __restrict__ lnb,
    float* __restrict__ h_out, float* __restrict__ c_out)
{
    __shared__ float4 comb4[16 * (CIN / 4)];
    __shared__ float zsh[16 * ZOUT];
    __shared__ float stat_s[16 * SD];
    float* combf = (float*)comb4;
    const int t = threadIdx.x;
    const int nb = blockIdx.x * 16;
    #pragma unroll
    for (int i = 0; i < 2; ++i) {
        int idx = t + i * 256;
        combf[(idx >> 5) * CIN + (idx & 31)] = x_g[(size_t)nb * XD + idx];
    }
    #pragma unroll
    for (int i = 0; i < 8; ++i) {
        int idx = t + i * 256;
        combf[(idx >> 7) * CIN + 32 + (idx & 127)] = hself_g[(size_t)nb * H + idx];
    }
    #pragma unroll
    for (int i = 0; i < 8; ++i) {
        int idx = t + i * 256;
        combf[(idx >> 7) * CIN + 160 + (idx & 127)] = nc[(size_t)nb * H + idx];
    }
    stat_s[t] = stat_g[(size_t)nb * SD + t];
    if (t < 16 * SD - 256) stat_s[t + 256] = stat_g[(size_t)nb * SD + t + 256];
    __syncthreads();
    {
        const int o = t & 127, jg = t >> 7;
        #pragma unroll
        for (int jj = 0; jj < 8; ++jj) {
            const int j = jg * 8 + jj;
            float s = bs[o];
            #pragma unroll
            for (int c = 0; c < SD; ++c) s += Ws[o * SD + c] * stat_s[j * SD + c];
            combf[j * CIN + 288 + o] = s;
        }
    }
    __syncthreads();
    float acc0[16], acc1[16];
    #pragma unroll
    for (int j = 0; j < 16; ++j) { acc0[j] = 0.f; acc1[j] = 0.f; }
    const float4* W0 = (const float4*)(Wl + (size_t)t * CIN);
    const float4* W1 = (const float4*)(Wl + (size_t)(t + 256) * CIN);
    for (int d4 = 0; d4 < CIN / 4; ++d4) {
        float4 w0 = W0[d4], w1 = W1[d4];
        #pragma unroll
        for (int j = 0; j < 16; ++j) {
            float4 cv = comb4[j * (CIN / 4) + d4];
            acc0[j] += dot4_(w0, cv);
            acc1[j] += dot4_(w1, cv);
        }
    }
    const float bl0 = bl[t], bl1 = bl[t + 256];
    #pragma unroll
    for (int j = 0; j < 16; ++j) {
        zsh[j * ZOUT + t] = acc0[j] + bl0;
        zsh[j * ZOUT + 256 + t] = acc1[j] + bl1;
    }
    __syncthreads();
    {
        const int h = t & 127, jg = t >> 7;
        #pragma unroll
        for (int jj = 0; jj < 8; ++jj) {
            const int j = jg * 8 + jj;
            const size_t n = (size_t)(nb + j);
            float zi = zsh[j * ZOUT + h];
            float zf = zsh[j * ZOUT + 128 + h];
            float zo = zsh[j * ZOUT + 256 + h];
            float zg = zsh[j * ZOUT + 384 + h];
            float cn = sigmoidf_(zf) * cself_g[n * H + h] + sigmoidf_(zi) * tanhf(zg);
            c_out[n * H + h] = cn;
            zsh[j * ZOUT + h] = sigmoidf_(zo) * tanhf(cn);
        }
    }
    __syncthreads();
    {
        const int w = t >> 6, lane = t & 63;
        #pragma unroll
        for (int jj = 0; jj < 4; ++jj) {
            const int j = w * 4 + jj;
            const size_t n = (size_t)(nb + j);
            float a = zsh[j * ZOUT + lane];
            float b = zsh[j * ZOUT + 64 + lane];
            float s = a + b, q = a * a + b * b;
            #pragma unroll
            for (int off = 1; off < 64; off <<= 1) {
                s += __shfl_xor(s, off);
                q += __shfl_xor(q, off);
            }
            float mu = s * (1.0f / 128.0f);
            float var = q * (1.0f / 128.0f) - mu * mu;
            float rstd = rsqrtf(var + 1e-5f);
            h_out[n * H + lane] = (a - mu) * rstd * lnw[lane] + lnb[lane];
            h_out[n * H + 64 + lane] = (b - mu) * rstd * lnw[64 + lane] + lnb[64 + lane];
        }
    }
}

extern "C" void kernel_launch(void* const* d_in, const int* in_sizes, int n_in,
                              void* d_out, int out_size, void* d_ws, size_t ws_size,
                              hipStream_t stream) {
    const float* x      = (const float*)d_in[0];
    const float* h_self = (const float*)d_in[1];
    const float* c_self = (const float*)d_in[2];
    const float* h_inf  = (const float*)d_in[3];
    const unsigned char* valid = (const unsigned char*)d_in[4];
    const float* statp  = (const float*)d_in[5];
    const float* Wn     = (const float*)d_in[6];
    const float* Wg     = (const float*)d_in[7];
    const float* bg     = (const float*)d_in[8];
    const float* Ws     = (const float*)d_in[9];
    const float* bs     = (const float*)d_in[10];
    const float* Wl     = (const float*)d_in[11];
    const float* bl     = (const float*)d_in[12];
    const float* lnw    = (const float*)d_in[13];
    const float* lnb    = (const float*)d_in[14];

    float* h_out = (float*)d_out;
    float* c_out = h_out + (size_t)NN * H;

    const size_t W_BYTES = (size_t)512 * CIN2 * 2 + 16384 * 2 + 32768 * 2 + 512 * 4;
    const size_t NC_BYTES = (size_t)NN * H * 2;

    if (ws_size >= W_BYTES) {
        char* p = (char*)d_ws;
        unsigned short* WpB = (unsigned short*)p;           p += (size_t)512 * CIN2 * 2;
        unsigned short* WnB = (unsigned short*)p;           p += 16384 * 2;
        unsigned short* WgB = (unsigned short*)p;           p += 32768 * 2;
        float* bp = (float*)p;                              p += 512 * 4;

        unsigned short* ncb;
        int nc_stride;
        if (ws_size >= W_BYTES + NC_BYTES + 64) {
            ncb = (unsigned short*)p;
            nc_stride = H;
        } else {
            // overlay: nc row n = first 256B of h_out row n; k_lstm reads its
            // own rows before writing them (block-local).
            ncb = (unsigned short*)h_out;
            nc_stride = 256;
        }

        k_prep<<<576, 256, 0, stream>>>(Wn, Wg, Wl, bl, Ws, bs,
                                        WnB, WgB, WpB, bp);
        k_nb_mfma<<<512, 256, 0, stream>>>(h_self, h_inf, valid, WnB, WgB, bg,
                                           ncb, nc_stride);
        k_lstm_mfma<<<(NN + MB_LSTM - 1) / MB_LSTM, 256, 0, stream>>>(
            x, h_self, c_self, statp, ncb, nc_stride, WpB, bp,
            lnw, lnb, h_out, c_out);
    } else {
        float* nc_buf = (ws_size >= (size_t)NN * H * sizeof(float))
                            ? (float*)d_ws : h_out;
        k_nb_f32<<<NN / 8, 256, 0, stream>>>(h_self, h_inf, valid, Wn, Wg, bg, nc_buf);
        k_lstm_f32<<<NN / 16, 256, 0, stream>>>(x, h_self, c_self, statp, nc_buf,
                                                Ws, bs, Wl, bl, lnw, lnb, h_out, c_out);
    }
}

// Round 4
// 180.816 us; speedup vs baseline: 8.2262x; 1.0618x over previous
//
#include <hip/hip_runtime.h>
#include <hip/hip_bf16.h>

#define NN 50000
#define KI 8
#define H 128
#define XD 32
#define SD 27
#define CIN 416      // original combined width
#define CIN2 320     // fused combined: x(32)|h(128)|nc(128)|static(27)|pad(5)
#define CPAD 328     // LDS row stride (shorts)
#define ZOUT 512
#define NTILE_NB (NN / KI)   // 6250 tiles of 8 nodes
#define MB_LSTM 32           // nodes per k_lstm block

typedef __attribute__((ext_vector_type(8))) short bf16x8;
typedef __attribute__((ext_vector_type(4))) float f32x4;
typedef __attribute__((ext_vector_type(4))) unsigned short us4;

#define MFMA16(a, b, c) __builtin_amdgcn_mfma_f32_16x16x32_bf16((a), (b), (c), 0, 0, 0)

static __device__ __forceinline__ float sigmoidf_(float x) {
    return 1.0f / (1.0f + __expf(-x));
}
// fast tanh, saturation-safe: 1 - 2/(e^{2x}+1)
static __device__ __forceinline__ float tanhf_(float x) {
    return 1.0f - 2.0f / (__expf(2.0f * x) + 1.0f);
}
static __device__ __forceinline__ unsigned short f2b(float f) {
    union { float f; unsigned int u; } v; v.f = f;
    unsigned int r = v.u + 0x7FFF + ((v.u >> 16) & 1);
    return (unsigned short)(r >> 16);
}
static __device__ __forceinline__ float dot4_(float4 a, float4 b) {
    return a.x * b.x + a.y * b.y + a.z * b.z + a.w * b.w;
}

// ---------------------------------------------------------------------------
// Prep: bf16 weights + fused LSTM weight W' and bias b'.
// ---------------------------------------------------------------------------
__global__ __launch_bounds__(256) void k_prep(
    const float* __restrict__ Wn, const float* __restrict__ Wg,
    const float* __restrict__ Wl, const float* __restrict__ bl,
    const float* __restrict__ Ws, const float* __restrict__ bs,
    unsigned short* __restrict__ WnB, unsigned short* __restrict__ WgB,
    unsigned short* __restrict__ WpB, float* __restrict__ bp)
{
    const int b = blockIdx.x, t = threadIdx.x;
    if (b < 512) {
        const float* wr = Wl + (size_t)b * CIN;
        unsigned short* out = WpB + (size_t)b * CIN2;
        for (int c = t; c < CIN2; c += 256) {
            float v;
            if (c < 288) v = wr[c];
            else if (c < 288 + SD) {
                int s = c - 288;
                float acc = 0.f;
                for (int j = 0; j < H; ++j) acc += wr[288 + j] * Ws[j * SD + s];
                v = acc;
            } else v = 0.f;
            out[c] = f2b(v);
        }
        if (t == 0) {
            float acc = bl[b];
            for (int j = 0; j < H; ++j) acc += wr[288 + j] * bs[j];
            bp[b] = acc;
        }
    } else {
        int idx = (b - 512) * 256 + t;
        for (int r = idx; r < 49152; r += 16384) {
            if (r < 16384) WnB[r] = f2b(Wn[r]);
            else WgB[r - 16384] = f2b(Wg[r - 16384]);
        }
    }
}

// ---------------------------------------------------------------------------
// Neighbor context: persistent weight registers, grid-stride over 8-node tiles.
// ---------------------------------------------------------------------------
__global__ __launch_bounds__(256, 2) void k_nb_mfma(
    const float* __restrict__ hself_g, const float* __restrict__ hin_g,
    const unsigned char* __restrict__ valid_raw,
    const unsigned short* __restrict__ WnB, const unsigned short* __restrict__ WgB,
    const float* __restrict__ bg,
    unsigned short* __restrict__ ncb, int nc_stride)
{
    __shared__ unsigned short hin_s[64 * 128];  // XOR-swizzled, 16KB
    __shared__ unsigned short hs_s[8 * 128];    // XOR-swizzled, 2KB
    __shared__ float gh_s[8][128];              // 4KB
    __shared__ unsigned short ncs[8 * 128];     // 2KB
    __shared__ float valid_s[64];

    const int t = threadIdx.x;
    const int w = t >> 6, l = t & 63;
    const int ln = l & 15, lk = l >> 4;

    int det = 0;
    #pragma unroll
    for (int i = 0; i < 64; ++i) det |= valid_raw[4 * i + 1];
    const bool f8 = (det != 0);

    bf16x8 Bn[2][4], Ba[2][4], Bb[2][4];
    const int cbase = w * 32;
    #pragma unroll
    for (int c = 0; c < 2; ++c) {
        const int col = cbase + c * 16 + ln;
        #pragma unroll
        for (int kk = 0; kk < 4; ++kk) {
            const int k0 = kk * 32 + lk * 8;
            Bn[c][kk] = *(const bf16x8*)(WnB + col * H + k0);
            Ba[c][kk] = *(const bf16x8*)(WgB + col * 2 * H + k0);
            Bb[c][kk] = *(const bf16x8*)(WgB + col * 2 * H + H + k0);
        }
    }
    const float bg0 = bg[cbase + ln];
    const float bg1 = bg[cbase + 16 + ln];

    for (int tile = blockIdx.x; tile < NTILE_NB; tile += gridDim.x) {
        const int nb = tile * 8;

        if (t < 64) {
            bool v = f8 ? (valid_raw[(size_t)nb * KI + t] != 0)
                        : (((const unsigned int*)valid_raw)[(size_t)nb * KI + t] != 0u);
            valid_s[t] = v ? 1.f : 0.f;
        }
        {
            const float4* src = (const float4*)(hin_g + (size_t)nb * KI * H);
            float4 r0[8];
            #pragma unroll
            for (int i = 0; i < 8; ++i) r0[i] = src[t + i * 256];
            float4 hv = ((const float4*)(hself_g + (size_t)nb * H))[t];
            #pragma unroll
            for (int i = 0; i < 8; ++i) {
                int e = (t + i * 256) * 4, row = e >> 7, col = e & 127;
                unsigned byte = (unsigned)(row * 256 + col * 2) ^ (unsigned)((row & 7) << 4);
                us4 pk = { f2b(r0[i].x), f2b(r0[i].y), f2b(r0[i].z), f2b(r0[i].w) };
                *(us4*)((char*)hin_s + byte) = pk;
            }
            {
                int e = t * 4, row = e >> 7, col = e & 127;
                unsigned byte = (unsigned)(row * 256 + col * 2) ^ (unsigned)((row & 7) << 4);
                us4 pk = { f2b(hv.x), f2b(hv.y), f2b(hv.z), f2b(hv.w) };
                *(us4*)((char*)hs_s + byte) = pk;
            }
        }
        __syncthreads();

        f32x4 accM[4][2], accP[4][2], accG[2];
        #pragma unroll
        for (int m = 0; m < 4; ++m)
            #pragma unroll
            for (int c = 0; c < 2; ++c) { accM[m][c] = (f32x4)0.f; accP[m][c] = (f32x4)0.f; }
        accG[0] = (f32x4)0.f; accG[1] = (f32x4)0.f;

        #pragma unroll
        for (int kk = 0; kk < 4; ++kk) {
            const int k0 = kk * 32 + lk * 8;
            bf16x8 am[4];
            #pragma unroll
            for (int m = 0; m < 4; ++m) {
                int row = m * 16 + ln;
                unsigned byte = (unsigned)(row * 256 + k0 * 2) ^ (unsigned)((row & 7) << 4);
                am[m] = *(const bf16x8*)((const char*)hin_s + byte);
            }
            bf16x8 ah;
            {
                int row = ln & 7;
                unsigned byte = (unsigned)(row * 256 + k0 * 2) ^ (unsigned)((row & 7) << 4);
                ah = *(const bf16x8*)((const char*)hs_s + byte);
            }
            #pragma unroll
            for (int m = 0; m < 4; ++m)
                #pragma unroll
                for (int c = 0; c < 2; ++c) {
                    accM[m][c] = MFMA16(am[m], Bn[c][kk], accM[m][c]);
                    accP[m][c] = MFMA16(am[m], Ba[c][kk], accP[m][c]);
                }
            accG[0] = MFMA16(ah, Bb[0][kk], accG[0]);
            accG[1] = MFMA16(ah, Bb[1][kk], accG[1]);
        }

        #pragma unroll
        for (int c = 0; c < 2; ++c)
            #pragma unroll
            for (int r = 0; r < 4; ++r) {
                int row = lk * 4 + r;
                if (row < 8) gh_s[row][cbase + c * 16 + ln] = accG[c][r];
            }
        __syncthreads();

        #pragma unroll
        for (int m = 0; m < 4; ++m) {
            const int node = 2 * m + (lk >> 1);
            #pragma unroll
            for (int c = 0; c < 2; ++c) {
                const int col = cbase + c * 16 + ln;
                const float bgc = c ? bg1 : bg0;
                const float ghv = gh_s[node][col];
                float sum = 0.f;
                #pragma unroll
                for (int r = 0; r < 4; ++r) {
                    int row = m * 16 + lk * 4 + r;
                    float g = sigmoidf_(accP[m][c][r] + ghv + bgc);
                    sum += valid_s[row] * g * accM[m][c][r];
                }
                sum += __shfl_xor(sum, 16);
                if ((l & 16) == 0) ncs[(2 * m + (l >> 5)) * H + col] = f2b(sum);
            }
        }
        __syncthreads();

        {
            int e = t * 4, node = e >> 7, col = e & 127;
            us4 v = *(const us4*)(ncs + e);
            *(us4*)(ncb + (size_t)(nb + node) * nc_stride + col) = v;
        }
        __syncthreads();
    }
}

// ---------------------------------------------------------------------------
// LSTM via MFMA. 32 nodes/block, 512 threads (8 waves), low-register design:
// wave w owns z-cols [w*16, w*16+16) of ALL 4 gates -> acc = 2x4 f32x4 = 32 regs.
// c_self prefetched into regs before GEMM (latency hidden under MFMA).
// ---------------------------------------------------------------------------
__global__ __launch_bounds__(512, 4) void k_lstm_mfma(
    const float* __restrict__ x_g, const float* __restrict__ hself_g,
    const float* __restrict__ cself_g, const float* __restrict__ stat_g,
    const unsigned short* __restrict__ ncb, int nc_stride,
    const unsigned short* __restrict__ WpB, const float* __restrict__ bp,
    const float* __restrict__ lnw, const float* __restrict__ lnb,
    float* __restrict__ h_out, float* __restrict__ c_out)
{
    __shared__ char smem[MB_LSTM * CPAD * 2];      // 21KB
    unsigned short* comb = (unsigned short*)smem;  // [32][328] bf16
    float (*hpre)[132] = (float(*)[132])smem;      // union after GEMM (16.9KB)

    const int t = threadIdx.x;
    const int nb = blockIdx.x * MB_LSTM;
    const int w = t >> 6, l = t & 63, ln = l & 15, lk = l >> 4;
    const int hcol = w * 16 + ln;

    // ---- stage comb' = [x | h_self | nc | static | 0] as bf16 ----
    if (t < 256) {  // x: 32*32 f32 = 256 float4
        int e = t * 4, row = e >> 5, col = e & 31;
        us4 pk = { 0, 0, 0, 0 };
        if (nb + row < NN) {
            float4 v = ((const float4*)(x_g + (size_t)nb * XD))[t];
            pk = us4{ f2b(v.x), f2b(v.y), f2b(v.z), f2b(v.w) };
        }
        *(us4*)(comb + row * CPAD + col) = pk;
    }
    #pragma unroll
    for (int i = 0; i < 2; ++i) {  // h_self: 32*128 f32 = 1024 float4
        int p4 = t + i * 512;
        int e = p4 * 4, row = e >> 7, col = 32 + (e & 127);
        us4 pk = { 0, 0, 0, 0 };
        if (nb + row < NN) {
            float4 v = ((const float4*)(hself_g + (size_t)nb * H))[p4];
            pk = us4{ f2b(v.x), f2b(v.y), f2b(v.z), f2b(v.w) };
        }
        *(us4*)(comb + row * CPAD + col) = pk;
    }
    #pragma unroll
    for (int i = 0; i < 2; ++i) {  // nc: 32*128 bf16 = 1024 us4
        int p4 = t + i * 512;
        int e = p4 * 4, row = e >> 7, col = e & 127;
        us4 v = { 0, 0, 0, 0 };
        if (nb + row < NN) v = *(const us4*)(ncb + (size_t)(nb + row) * nc_stride + col);
        *(us4*)(comb + row * CPAD + 160 + col) = v;
    }
    for (int i = t; i < MB_LSTM * SD; i += 512) {  // static: 32*27 f32
        int row = i / SD, col = i - row * SD;
        unsigned short v = 0;
        if (nb + row < NN) v = f2b(stat_g[(size_t)(nb + row) * SD + col]);
        comb[row * CPAD + 288 + col] = v;
    }
    if (t < MB_LSTM * 5) {  // zero pad cols 315..319
        int row = t / 5, col = 315 + t % 5;
        comb[row * CPAD + col] = 0;
    }

    // ---- c_self prefetch (8 scalars/thread) — latency hides under GEMM ----
    float cpre[8];
    #pragma unroll
    for (int m = 0; m < 2; ++m)
        #pragma unroll
        for (int r = 0; r < 4; ++r) {
            int node = m * 16 + lk * 4 + r;
            size_t n = (size_t)(nb + node);
            cpre[m * 4 + r] = (n < NN) ? cself_g[n * H + hcol] : 0.f;
        }
    __syncthreads();

    // ---- GEMM: z[32 x 512] = comb' @ W'^T ----
    f32x4 acc[2][4];  // [m-tile][gate]
    #pragma unroll
    for (int m = 0; m < 2; ++m)
        #pragma unroll
        for (int g = 0; g < 4; ++g) acc[m][g] = (f32x4)0.f;

    #pragma unroll
    for (int kk = 0; kk < 10; ++kk) {
        const int k0 = kk * 32 + lk * 8;
        bf16x8 a0 = *(const bf16x8*)(comb + ln * CPAD + k0);
        bf16x8 a1 = *(const bf16x8*)(comb + (16 + ln) * CPAD + k0);
        #pragma unroll
        for (int g = 0; g < 4; ++g) {
            bf16x8 b = *(const bf16x8*)(WpB + (size_t)(g * H + hcol) * CIN2 + k0);
            acc[0][g] = MFMA16(a0, b, acc[0][g]);
            acc[1][g] = MFMA16(a1, b, acc[1][g]);
        }
    }
    __syncthreads();  // comb reads done; hpre may overwrite

    // ---- LSTM elementwise ----
    {
        const float bi = bp[hcol], bf = bp[H + hcol];
        const float bo = bp[2 * H + hcol], bgg = bp[3 * H + hcol];
        #pragma unroll
        for (int m = 0; m < 2; ++m)
            #pragma unroll
            for (int r = 0; r < 4; ++r) {
                int node = m * 16 + lk * 4 + r;
                size_t n = (size_t)(nb + node);
                if (n < NN) {
                    float zi = acc[m][0][r] + bi;
                    float zf = acc[m][1][r] + bf;
                    float zo = acc[m][2][r] + bo;
                    float zg = acc[m][3][r] + bgg;
                    float cn = sigmoidf_(zf) * cpre[m * 4 + r] + sigmoidf_(zi) * tanhf_(zg);
                    c_out[n * H + hcol] = cn;
                    hpre[node][hcol] = sigmoidf_(zo) * tanhf_(cn);
                }
            }
    }
    __syncthreads();

    // ---- LayerNorm over H=128, 8 waves x 4 nodes ----
    #pragma unroll
    for (int jj = 0; jj < 4; ++jj) {
        const int j = w * 4 + jj;
        const size_t n = (size_t)(nb + j);
        if (n < NN) {
            float a = hpre[j][l];
            float b = hpre[j][64 + l];
            float s = a + b, q = a * a + b * b;
            #pragma unroll
            for (int off = 1; off < 64; off <<= 1) {
                s += __shfl_xor(s, off);
                q += __shfl_xor(q, off);
            }
            float mu = s * (1.0f / 128.0f);
            float var = q * (1.0f / 128.0f) - mu * mu;
            float rstd = rsqrtf(var + 1e-5f);
            h_out[n * H + l]      = (a - mu) * rstd * lnw[l] + lnb[l];
            h_out[n * H + 64 + l] = (b - mu) * rstd * lnw[64 + l] + lnb[64 + l];
        }
    }
}

// ---------------------------------------------------------------------------
// f32 fallback path — used only if ws is too small.
// ---------------------------------------------------------------------------
__global__ __launch_bounds__(256) void k_nb_f32(
    const float* __restrict__ hself_g, const float* __restrict__ hin_g,
    const unsigned char* __restrict__ valid_raw,
    const float* __restrict__ Wn, const float* __restrict__ Wg,
    const float* __restrict__ bg, float* __restrict__ nc)
{
    __shared__ float4 hin_s[8 * KI * (H / 4)];
    __shared__ float4 hs_s[8 * (H / 4)];
    __shared__ int flag8;
    const int t = threadIdx.x;
    const int nb = blockIdx.x * 8;
    {
        int loc = 0;
        if (t < 64) {
            #pragma unroll
            for (int i = 0; i < 16; ++i) loc |= valid_raw[4 * (t * 16 + i) + 1];
        }
        int any = __any(loc != 0);
        if (t == 0) flag8 = any;
    }
    const float4* src_hin = (const float4*)(hin_g + (size_t)nb * KI * H);
    #pragma unroll
    for (int i = 0; i < 8; ++i) hin_s[t + i * 256] = src_hin[t + i * 256];
    hs_s[t] = ((const float4*)(hself_g + (size_t)nb * H))[t];
    __syncthreads();
    const int o = t & 127, g = t >> 7;
    float msg[4][KI], gat[4][KI], gh[4];
    #pragma unroll
    for (int j = 0; j < 4; ++j) {
        gh[j] = 0.f;
        #pragma unroll
        for (int k = 0; k < KI; ++k) { msg[j][k] = 0.f; gat[j][k] = 0.f; }
    }
    const float4* Wn4 = (const float4*)(Wn + (size_t)o * H);
    const float4* Wg4a = (const float4*)(Wg + (size_t)o * 2 * H);
    const float4* Wg4b = (const float4*)(Wg + (size_t)o * 2 * H + H);
    for (int d4 = 0; d4 < H / 4; ++d4) {
        float4 wn = Wn4[d4], w0 = Wg4a[d4], w1 = Wg4b[d4];
        #pragma unroll
        for (int j = 0; j < 4; ++j) {
            const int node = g * 4 + j;
            gh[j] += dot4_(w1, hs_s[node * 32 + d4]);
            #pragma unroll
            for (int k = 0; k < KI; ++k) {
                float4 hv = hin_s[(node * KI + k) * 32 + d4];
                msg[j][k] += dot4_(wn, hv);
                gat[j][k] += dot4_(w0, hv);
            }
        }
    }
    const float bgo = bg[o];
    const unsigned int* valid32 = (const unsigned int*)valid_raw;
    const int f8 = flag8;
    #pragma unroll
    for (int j = 0; j < 4; ++j) {
        const int n = nb + g * 4 + j;
        float acc = 0.f;
        #pragma unroll
        for (int k = 0; k < KI; ++k) {
            bool v = f8 ? (valid_raw[n * KI + k] != 0) : (valid32[n * KI + k] != 0u);
            if (v) acc += sigmoidf_(gat[j][k] + gh[j] + bgo) * msg[j][k];
        }
        nc[(size_t)n * H + o] = acc;
    }
}

__global__ __launch_bounds__(256) void k_lstm_f32(
    const float* __restrict__ x_g, const float* __restrict__ hself_g,
    const float* __restrict__ cself_g, const float* __restrict__ stat_g,
    const float* __restrict__ nc,
    const float* __restrict__ Ws, const float* __restrict__ bs,
    const float* __restrict__ Wl, const float* __restrict__ bl,
    const float* __restrict__ lnw, const float* __restrict__ lnb,
    float* __restrict__ h_out, float* __restrict__ c_out)
{
    __shared__ float4 comb4[16 * (CIN / 4)];
    __shared__ float zsh[16 * ZOUT];
    __shared__ float stat_s[16 * SD];
    float* combf = (float*)comb4;
    const int t = threadIdx.x;
    const int nb = blockIdx.x * 16;
    #pragma unroll
    for (int i = 0; i < 2; ++i) {
        int idx = t + i * 256;
        combf[(idx >> 5) * CIN + (idx & 31)] = x_g[(size_t)nb * XD + idx];
    }
    #pragma unroll
    for (int i = 0; i < 8; ++i) {
        int idx = t + i * 256;
        combf[(idx >> 7) * CIN + 32 + (idx & 127)] = hself_g[(size_t)nb * H + idx];
    }
    #pragma unroll
    for (int i = 0; i < 8; ++i) {
        int idx = t + i * 256;
        combf[(idx >> 7) * CIN + 160 + (idx & 127)] = nc[(size_t)nb * H + idx];
    }
    stat_s[t] = stat_g[(size_t)nb * SD + t];
    if (t < 16 * SD - 256) stat_s[t + 256] = stat_g[(size_t)nb * SD + t + 256];
    __syncthreads();
    {
        const int o = t & 127, jg = t >> 7;
        #pragma unroll
        for (int jj = 0; jj < 8; ++jj) {
            const int j = jg * 8 + jj;
            float s = bs[o];
            #pragma unroll
            for (int c = 0; c < SD; ++c) s += Ws[o * SD + c] * stat_s[j * SD + c];
            combf[j * CIN + 288 + o] = s;
        }
    }
    __syncthreads();
    float acc0[16], acc1[16];
    #pragma unroll
    for (int j = 0; j < 16; ++j) { acc0[j] = 0.f; acc1[j] = 0.f; }
    const float4* W0 = (const float4*)(Wl + (size_t)t * CIN);
    const float4* W1 = (const float4*)(Wl + (size_t)(t + 256) * CIN);
    for (int d4 = 0; d4 < CIN / 4; ++d4) {
        float4 w0 = W0[d4], w1 = W1[d4];
        #pragma unroll
        for (int j = 0; j < 16; ++j) {
            float4 cv = comb4[j * (CIN / 4) + d4];
            acc0[j] += dot4_(w0, cv);
            acc1[j] += dot4_(w1, cv);
        }
    }
    const float bl0 = bl[t], bl1 = bl[t + 256];
    #pragma unroll
    for (int j = 0; j < 16; ++j) {
        zsh[j * ZOUT + t] = acc0[j] + bl0;
        zsh[j * ZOUT + 256 + t] = acc1[j] + bl1;
    }
    __syncthreads();
    {
        const int h = t & 127, jg = t >> 7;
        #pragma unroll
        for (int jj = 0; jj < 8; ++jj) {
            const int j = jg * 8 + jj;
            const size_t n = (size_t)(nb + j);
            float zi = zsh[j * ZOUT + h];
            float zf = zsh[j * ZOUT + 128 + h];
            float zo = zsh[j * ZOUT + 256 + h];
            float zg = zsh[j * ZOUT + 384 + h];
            float cn = sigmoidf_(zf) * cself_g[n * H + h] + sigmoidf_(zi) * tanhf(zg);
            c_out[n * H + h] = cn;
            zsh[j * ZOUT + h] = sigmoidf_(zo) * tanhf(cn);
        }
    }
    __syncthreads();
    {
        const int w = t >> 6, lane = t & 63;
        #pragma unroll
        for (int jj = 0; jj < 4; ++jj) {
            const int j = w * 4 + jj;
            const size_t n = (size_t)(nb + j);
            float a = zsh[j * ZOUT + lane];
            float b = zsh[j * ZOUT + 64 + lane];
            float s = a + b, q = a * a + b * b;
            #pragma unroll
            for (int off = 1; off < 64; off <<= 1) {
                s += __shfl_xor(s, off);
                q += __shfl_xor(q, off);
            }
            float mu = s * (1.0f / 128.0f);
            float var = q * (1.0f / 128.0f) - mu * mu;
            float rstd = rsqrtf(var + 1e-5f);
            h_out[n * H + lane] = (a - mu) * rstd * lnw[lane] + lnb[lane];
            h_out[n * H + 64 + lane] = (b - mu) * rstd * lnw[64 + lane] + lnb[64 + lane];
        }
    }
}

extern "C" void kernel_launch(void* const* d_in, const int* in_sizes, int n_in,
                              void* d_out, int out_size, void* d_ws, size_t ws_size,
                              hipStream_t stream) {
    const float* x      = (const float*)d_in[0];
    const float* h_self = (const float*)d_in[1];
    const float* c_self = (const float*)d_in[2];
    const float* h_inf  = (const float*)d_in[3];
    const unsigned char* valid = (const unsigned char*)d_in[4];
    const float* statp  = (const float*)d_in[5];
    const float* Wn     = (const float*)d_in[6];
    const float* Wg     = (const float*)d_in[7];
    const float* bg     = (const float*)d_in[8];
    const float* Ws     = (const float*)d_in[9];
    const float* bs     = (const float*)d_in[10];
    const float* Wl     = (const float*)d_in[11];
    const float* bl     = (const float*)d_in[12];
    const float* lnw    = (const float*)d_in[13];
    const float* lnb    = (const float*)d_in[14];

    float* h_out = (float*)d_out;
    float* c_out = h_out + (size_t)NN * H;

    const size_t W_BYTES = (size_t)512 * CIN2 * 2 + 16384 * 2 + 32768 * 2 + 512 * 4;
    const size_t NC_BYTES = (size_t)NN * H * 2;

    if (ws_size >= W_BYTES) {
        char* p = (char*)d_ws;
        unsigned short* WpB = (unsigned short*)p;           p += (size_t)512 * CIN2 * 2;
        unsigned short* WnB = (unsigned short*)p;           p += 16384 * 2;
        unsigned short* WgB = (unsigned short*)p;           p += 32768 * 2;
        float* bp = (float*)p;                              p += 512 * 4;

        unsigned short* ncb;
        int nc_stride;
        if (ws_size >= W_BYTES + NC_BYTES + 64) {
            ncb = (unsigned short*)p;
            nc_stride = H;
        } else {
            ncb = (unsigned short*)h_out;
            nc_stride = 256;
        }

        k_prep<<<576, 256, 0, stream>>>(Wn, Wg, Wl, bl, Ws, bs,
                                        WnB, WgB, WpB, bp);
        k_nb_mfma<<<512, 256, 0, stream>>>(h_self, h_inf, valid, WnB, WgB, bg,
                                           ncb, nc_stride);
        k_lstm_mfma<<<(NN + MB_LSTM - 1) / MB_LSTM, 512, 0, stream>>>(
            x, h_self, c_self, statp, ncb, nc_stride, WpB, bp,
            lnw, lnb, h_out, c_out);
    } else {
        float* nc_buf = (ws_size >= (size_t)NN * H * sizeof(float))
                            ? (float*)d_ws : h_out;
        k_nb_f32<<<NN / 8, 256, 0, stream>>>(h_self, h_inf, valid, Wn, Wg, bg, nc_buf);
        k_lstm_f32<<<NN / 16, 256, 0, stream>>>(x, h_self, c_self, statp, nc_buf,
                                                Ws, bs, Wl, bl, lnw, lnb, h_out, c_out);
    }
}